// Round 6
// baseline (42.893 us; speedup 1.0000x reference)
//
#include <hip/hip_runtime.h>
#include <hip/hip_cooperative_groups.h>
#include <math.h>

namespace cg = cooperative_groups;

// Cox negative log partial likelihood, bucketed (os_time in [0,3650)).
// Single cooperative dispatch:
//   phase 1: HB blocks, 2 samples/thread; per-block private LDS histograms of
//            exp(theta) and event-counts + per-block sum(theta over events);
//            blocks 1..HB-1 write partials to disjoint d_ws slices.
//   grid.sync()
//   phase 2: block 0 reuses its own LDS histogram + unrolled loads of the
//            other partials, register suffix-scan, and
//            sum_events log(rss) == sum_t cnt[t]*log(suffix[t]).
// Fallback: the proven 2-kernel path if cooperative launch is unavailable.

#define HSIZE 4096          // pow2 >= 3650, zero-padded
#define T1 1024
#define SPT 2               // samples per thread in phase 1
#define NW1 (T1 / 64)

// ---------- shared phase bodies ----------

__device__ __forceinline__ void phase1_hist(
    const float* __restrict__ risk, const int* __restrict__ os,
    const int* __restrict__ os_time, float* __restrict__ ws,
    int N, int HBn, float* he, float* hc, float* wred, int bid)
{
    const int tid  = threadIdx.x;
    const int lane = tid & 63;
    const int wid  = tid >> 6;

    // zero LDS: T1*4 == HSIZE
    *(float4*)&he[tid * 4] = make_float4(0.f, 0.f, 0.f, 0.f);
    *(float4*)&hc[tid * 4] = make_float4(0.f, 0.f, 0.f, 0.f);

    const int i0 = (bid * T1 + tid) * SPT;
    float th[SPT]; int tt[SPT]; int ee[SPT]; bool va[SPT];
    if (i0 + SPT - 1 < N) {
        float2 r2 = *(const float2*)&risk[i0];
        int2   t2 = *(const int2*)&os_time[i0];
        int2   e2 = *(const int2*)&os[i0];
        th[0] = r2.x; th[1] = r2.y;
        tt[0] = t2.x; tt[1] = t2.y;
        ee[0] = e2.x; ee[1] = e2.y;
        va[0] = va[1] = true;
    } else {
        #pragma unroll
        for (int k = 0; k < SPT; ++k) {
            int i = i0 + k;
            va[k] = i < N;
            th[k] = va[k] ? risk[i] : 0.f;
            tt[k] = va[k] ? os_time[i] : 0;
            ee[k] = va[k] ? os[i] : 0;
        }
    }
    float ex[SPT];
    #pragma unroll
    for (int k = 0; k < SPT; ++k) ex[k] = __expf(th[k]);
    __syncthreads();                        // LDS zeroed

    #pragma unroll
    for (int k = 0; k < SPT; ++k) {
        if (va[k]) {
            atomicAdd(&he[tt[k]], ex[k]);
            if (ee[k]) atomicAdd(&hc[tt[k]], 1.0f);
        }
    }
    float num = 0.f;
    #pragma unroll
    for (int k = 0; k < SPT; ++k) if (va[k] && ee[k]) num += th[k];
    #pragma unroll
    for (int off = 32; off; off >>= 1) num += __shfl_down(num, off, 64);
    if (lane == 0) wred[wid] = num;
    __syncthreads();                        // atomics + wred complete

    if (tid == 0) {
        float s = 0.f;
        #pragma unroll
        for (int w = 0; w < NW1; ++w) s += wred[w];
        ws[(size_t)HBn * (2 * HSIZE) + bid] = s;
    }
}

// phase 2: e4/c4 already hold the combined histogram for this thread's 4
// buckets; Spart holds the (lane<HB) theta partials in wave 0.
__device__ __forceinline__ void phase2_finish(
    float4 e4, float4 c4, float Spart, float* __restrict__ out,
    float* wtot, float* wls, float* wcs)
{
    const int tid  = threadIdx.x;
    const int lane = tid & 63;
    const int wid  = tid >> 6;

    // inclusive suffix scan, registers + shuffles
    float s3 = e4.w;
    float s2 = e4.z + s3;
    float s1 = e4.y + s2;
    float s0 = e4.x + s1;
    float incl = s0;
    #pragma unroll
    for (int off = 1; off < 64; off <<= 1) {
        float o = __shfl_down(incl, off, 64);
        if (lane + off < 64) incl += o;
    }
    float exclLane = __shfl_down(incl, 1, 64);
    if (lane == 63) exclLane = 0.f;
    if (lane == 0) wtot[wid] = incl;
    __syncthreads();
    float exclWave = 0.f;
    for (int w = wid + 1; w < NW1; ++w) exclWave += wtot[w];
    const float add = exclWave + exclLane;
    s0 += add; s1 += add; s2 += add; s3 += add;

    float lsum = 0.f;
    lsum += (c4.x > 0.f) ? c4.x * __logf(s0) : 0.f;
    lsum += (c4.y > 0.f) ? c4.y * __logf(s1) : 0.f;
    lsum += (c4.z > 0.f) ? c4.z * __logf(s2) : 0.f;
    lsum += (c4.w > 0.f) ? c4.w * __logf(s3) : 0.f;
    float csum = c4.x + c4.y + c4.z + c4.w;

    // theta partial reduce (lanes < HB of wave 0 hold values; rest 0)
    float ssum = Spart;
    #pragma unroll
    for (int off = 32; off; off >>= 1) {
        lsum += __shfl_down(lsum, off, 64);
        csum += __shfl_down(csum, off, 64);
        ssum += __shfl_down(ssum, off, 64);
    }
    if (lane == 0) { wls[wid] = lsum; wcs[wid] = csum; wtot[wid] = ssum; }
    __syncthreads();
    if (tid == 0) {
        float L = 0.f, C = 0.f, S = 0.f;
        #pragma unroll
        for (int w = 0; w < NW1; ++w) { L += wls[w]; C += wcs[w]; S += wtot[w]; }
        out[0] = -(S - L) / C;
    }
}

// ---------- fused cooperative kernel ----------

template <int HBC>
__global__ __launch_bounds__(T1) void k_fused(
    const float* __restrict__ risk,
    const int*   __restrict__ os,
    const int*   __restrict__ os_time,
    float*       __restrict__ out,
    float*       __restrict__ ws,
    int N, int HBdyn)
{
    const int HBn = (HBC > 0) ? HBC : HBdyn;
    __shared__ float he[HSIZE];
    __shared__ float hc[HSIZE];
    __shared__ float wred[NW1];
    __shared__ float wls[NW1];
    __shared__ float wcs[NW1];

    const int tid = threadIdx.x;
    const int bid = blockIdx.x;

    phase1_hist(risk, os, os_time, ws, N, HBn, he, hc, wred, bid);

    // blocks != 0 publish their partial histograms (block 0's stays in LDS)
    if (bid != 0) {
        float* oe = ws + (size_t)bid * (2 * HSIZE);
        *(float4*)&oe[tid * 4]         = *(float4*)&he[tid * 4];
        *(float4*)&oe[HSIZE + tid * 4] = *(float4*)&hc[tid * 4];
    }
    __threadfence();                // release partials device-wide
    cg::this_grid().sync();

    if (bid != 0) return;

    // phase 2 (block 0 only)
    __threadfence();                // acquire

    // theta partials: lanes < HB load in parallel (one latency)
    float Spart = (tid < HBn) ? ws[(size_t)HBn * (2 * HSIZE) + tid] : 0.f;

    float4 e4 = *(float4*)&he[tid * 4];     // own partial from LDS
    float4 c4 = *(float4*)&hc[tid * 4];
    if constexpr (HBC > 0) {
        float4 ea[HBC > 1 ? HBC - 1 : 1], ca[HBC > 1 ? HBC - 1 : 1];
        #pragma unroll
        for (int b = 1; b < HBC; ++b) {
            const float* p = ws + (size_t)b * (2 * HSIZE);
            ea[b - 1] = *(const float4*)&p[tid * 4];
            ca[b - 1] = *(const float4*)&p[HSIZE + tid * 4];
        }
        #pragma unroll
        for (int b = 1; b < HBC; ++b) {
            e4.x += ea[b-1].x; e4.y += ea[b-1].y; e4.z += ea[b-1].z; e4.w += ea[b-1].w;
            c4.x += ca[b-1].x; c4.y += ca[b-1].y; c4.z += ca[b-1].z; c4.w += ca[b-1].w;
        }
    } else {
        for (int b = 1; b < HBn; ++b) {
            const float* p = ws + (size_t)b * (2 * HSIZE);
            const float4 a = *(const float4*)&p[tid * 4];
            const float4 c = *(const float4*)&p[HSIZE + tid * 4];
            e4.x += a.x; e4.y += a.y; e4.z += a.z; e4.w += a.w;
            c4.x += c.x; c4.y += c.y; c4.z += c.z; c4.w += c.w;
        }
    }
    __syncthreads();                // he/hc reads done before wred reuse? (distinct arrays; barrier orders LDS reuse of wred by phase2_finish)
    phase2_finish(e4, c4, Spart, out, wred, wls, wcs);
}

// ---------- fallback: proven 2-kernel path ----------

__global__ __launch_bounds__(T1) void k_hist(
    const float* __restrict__ risk,
    const int*   __restrict__ os,
    const int*   __restrict__ os_time,
    float*       __restrict__ ws,
    int N, int HB)
{
    __shared__ float he[HSIZE];
    __shared__ float hc[HSIZE];
    __shared__ float wred[NW1];
    const int tid = threadIdx.x;
    const int bid = blockIdx.x;

    phase1_hist(risk, os, os_time, ws, N, HB, he, hc, wred, bid);

    float* oe = ws + (size_t)bid * (2 * HSIZE);
    *(float4*)&oe[tid * 4]         = *(float4*)&he[tid * 4];
    *(float4*)&oe[HSIZE + tid * 4] = *(float4*)&hc[tid * 4];
}

template <int HBC>
__global__ __launch_bounds__(T1) void k_final(
    const float* __restrict__ ws, float* __restrict__ out, int HB)
{
    __shared__ float wtot[NW1];
    __shared__ float wls[NW1];
    __shared__ float wcs[NW1];
    const int tid = threadIdx.x;
    const int HBn = (HBC > 0) ? HBC : HB;

    float Spart = (tid < HBn) ? ws[(size_t)HBn * (2 * HSIZE) + tid] : 0.f;

    float4 e4 = make_float4(0.f, 0.f, 0.f, 0.f);
    float4 c4 = make_float4(0.f, 0.f, 0.f, 0.f);
    if constexpr (HBC > 0) {
        float4 ea[HBC], ca[HBC];
        #pragma unroll
        for (int b = 0; b < HBC; ++b) {
            const float* p = ws + (size_t)b * (2 * HSIZE);
            ea[b] = *(const float4*)&p[tid * 4];
            ca[b] = *(const float4*)&p[HSIZE + tid * 4];
        }
        #pragma unroll
        for (int b = 0; b < HBC; ++b) {
            e4.x += ea[b].x; e4.y += ea[b].y; e4.z += ea[b].z; e4.w += ea[b].w;
            c4.x += ca[b].x; c4.y += ca[b].y; c4.z += ca[b].z; c4.w += ca[b].w;
        }
    } else {
        for (int b = 0; b < HB; ++b) {
            const float* p = ws + (size_t)b * (2 * HSIZE);
            const float4 a = *(const float4*)&p[tid * 4];
            const float4 c = *(const float4*)&p[HSIZE + tid * 4];
            e4.x += a.x; e4.y += a.y; e4.z += a.z; e4.w += a.w;
            c4.x += c.x; c4.y += c.y; c4.z += c.z; c4.w += c.w;
        }
    }
    phase2_finish(e4, c4, Spart, out, wtot, wls, wcs);
}

extern "C" void kernel_launch(void* const* d_in, const int* in_sizes, int n_in,
                              void* d_out, int out_size, void* d_ws, size_t ws_size,
                              hipStream_t stream) {
    const float* risk    = (const float*)d_in[0];
    const int*   os      = (const int*)d_in[1];
    const int*   os_time = (const int*)d_in[2];
    float*       out     = (float*)d_out;
    float*       ws      = (float*)d_ws;
    int N  = in_sizes[0];
    int HB = (N + T1 * SPT - 1) / (T1 * SPT);   // 4 for N=8192

    if (HB == 4) {
        void* args[] = {(void*)&risk, (void*)&os, (void*)&os_time,
                        (void*)&out, (void*)&ws, (void*)&N, (void*)&HB};
        hipError_t e = hipLaunchCooperativeKernel(
            reinterpret_cast<const void*>(&k_fused<4>),
            dim3(HB), dim3(T1), args, 0, stream);
        if (e == hipSuccess) return;
        // fall through to 2-kernel path if cooperative launch unsupported
    }

    k_hist<<<HB, T1, 0, stream>>>(risk, os, os_time, ws, N, HB);
    if (HB == 4)      k_final<4><<<1, T1, 0, stream>>>(ws, out, HB);
    else if (HB == 8) k_final<8><<<1, T1, 0, stream>>>(ws, out, HB);
    else              k_final<0><<<1, T1, 0, stream>>>(ws, out, HB);
}

// Round 7
// 15.041 us; speedup vs baseline: 2.8516x; 2.8516x over previous
//
#include <hip/hip_runtime.h>
#include <math.h>

// Cox negative log partial likelihood, bucketed (os_time in [0,3650)).
// k1: HB=4 blocks, 2 samples/thread; per-block private LDS histograms of
//     exp(theta) and event-counts + per-block sum(theta over events)
//     -> disjoint d_ws slices (fully overwritten, no zeroing race).
// k2: one block, compile-time-unrolled partial-sum (all loads in flight),
//     register suffix-scan, sum_events log(rss) == sum_t cnt[t]*log(sfx[t]),
//     theta partials loaded in parallel by lanes 0..HB-1.
// (Cooperative single-dispatch fusion measured 42.9 us vs 14.8 us for this
//  2-kernel form -- hipLaunchCooperativeKernel costs ~30 us/replay. Reverted.)

#define HSIZE 4096          // pow2 >= 3650, zero-padded
#define T1 1024
#define SPT 2               // samples per thread in k1
#define NW1 (T1 / 64)

__global__ __launch_bounds__(T1) void k_hist(
    const float* __restrict__ risk,
    const int*   __restrict__ os,
    const int*   __restrict__ os_time,
    float*       __restrict__ ws,
    int N, int HB)
{
    __shared__ float he[HSIZE];   // sum of exp(theta) per bucket
    __shared__ float hc[HSIZE];   // event count per bucket
    __shared__ float wred[NW1];

    const int tid  = threadIdx.x;
    const int bid  = blockIdx.x;
    const int lane = tid & 63;
    const int wid  = tid >> 6;

    // zero LDS: T1*4 == HSIZE
    *(float4*)&he[tid * 4] = make_float4(0.f, 0.f, 0.f, 0.f);
    *(float4*)&hc[tid * 4] = make_float4(0.f, 0.f, 0.f, 0.f);

    // vectorized 2-sample load
    const int i0 = (bid * T1 + tid) * SPT;
    float th[SPT]; int tt[SPT]; int ee[SPT]; bool va[SPT];
    if (i0 + SPT - 1 < N) {
        float2 r2 = *(const float2*)&risk[i0];
        int2   t2 = *(const int2*)&os_time[i0];
        int2   e2 = *(const int2*)&os[i0];
        th[0] = r2.x; th[1] = r2.y;
        tt[0] = t2.x; tt[1] = t2.y;
        ee[0] = e2.x; ee[1] = e2.y;
        va[0] = va[1] = true;
    } else {
        #pragma unroll
        for (int k = 0; k < SPT; ++k) {
            int i = i0 + k;
            va[k] = i < N;
            th[k] = va[k] ? risk[i] : 0.f;
            tt[k] = va[k] ? os_time[i] : 0;
            ee[k] = va[k] ? os[i] : 0;
        }
    }
    float ex[SPT];
    #pragma unroll
    for (int k = 0; k < SPT; ++k) ex[k] = __expf(th[k]);
    __syncthreads();                        // LDS zeroed

    #pragma unroll
    for (int k = 0; k < SPT; ++k) {
        if (va[k]) {
            atomicAdd(&he[tt[k]], ex[k]);
            if (ee[k]) atomicAdd(&hc[tt[k]], 1.0f);
        }
    }
    // per-block sum of theta over events
    float num = 0.f;
    #pragma unroll
    for (int k = 0; k < SPT; ++k) if (va[k] && ee[k]) num += th[k];
    #pragma unroll
    for (int off = 32; off; off >>= 1) num += __shfl_down(num, off, 64);
    if (lane == 0) wred[wid] = num;
    __syncthreads();                        // atomics + wred complete

    float* oe = ws + (size_t)bid * (2 * HSIZE);
    *(float4*)&oe[tid * 4]         = *(float4*)&he[tid * 4];
    *(float4*)&oe[HSIZE + tid * 4] = *(float4*)&hc[tid * 4];
    if (tid == 0) {
        float s = 0.f;
        #pragma unroll
        for (int w = 0; w < NW1; ++w) s += wred[w];
        ws[(size_t)HB * (2 * HSIZE) + bid] = s;
    }
}

template <int HBC>
__global__ __launch_bounds__(T1) void k_final(
    const float* __restrict__ ws, float* __restrict__ out, int HB)
{
    __shared__ float wtot[NW1];   // suffix-scan wave totals
    __shared__ float wls[NW1];    // log-sum partials
    __shared__ float wcs[NW1];    // count partials
    __shared__ float wss[NW1];    // theta-sum partials (separate: no reuse race)

    const int tid  = threadIdx.x;
    const int lane = tid & 63;
    const int wid  = tid >> 6;
    const int HBn  = (HBC > 0) ? HBC : HB;

    // theta partials: lanes 0..HB-1 load in parallel (one latency exposure)
    float Spart = (tid < HBn) ? ws[(size_t)HBn * (2 * HSIZE) + tid] : 0.f;

    float4 e4 = make_float4(0.f, 0.f, 0.f, 0.f);
    float4 c4 = make_float4(0.f, 0.f, 0.f, 0.f);
    if constexpr (HBC > 0) {
        // compile-time bound: all loads issue before accumulation
        float4 ea[HBC], ca[HBC];
        #pragma unroll
        for (int b = 0; b < HBC; ++b) {
            const float* p = ws + (size_t)b * (2 * HSIZE);
            ea[b] = *(const float4*)&p[tid * 4];
            ca[b] = *(const float4*)&p[HSIZE + tid * 4];
        }
        #pragma unroll
        for (int b = 0; b < HBC; ++b) {
            e4.x += ea[b].x; e4.y += ea[b].y; e4.z += ea[b].z; e4.w += ea[b].w;
            c4.x += ca[b].x; c4.y += ca[b].y; c4.z += ca[b].z; c4.w += ca[b].w;
        }
    } else {
        for (int b = 0; b < HB; ++b) {
            const float* p = ws + (size_t)b * (2 * HSIZE);
            const float4 a = *(const float4*)&p[tid * 4];
            const float4 c = *(const float4*)&p[HSIZE + tid * 4];
            e4.x += a.x; e4.y += a.y; e4.z += a.z; e4.w += a.w;
            c4.x += c.x; c4.y += c.y; c4.z += c.z; c4.w += c.w;
        }
    }

    // inclusive suffix scan over HSIZE buckets, registers + shuffles
    float s3 = e4.w;
    float s2 = e4.z + s3;
    float s1 = e4.y + s2;
    float s0 = e4.x + s1;
    float incl = s0;
    #pragma unroll
    for (int off = 1; off < 64; off <<= 1) {
        float o = __shfl_down(incl, off, 64);
        if (lane + off < 64) incl += o;
    }
    float exclLane = __shfl_down(incl, 1, 64);
    if (lane == 63) exclLane = 0.f;
    if (lane == 0) wtot[wid] = incl;
    __syncthreads();
    float exclWave = 0.f;
    for (int w = wid + 1; w < NW1; ++w) exclWave += wtot[w];
    const float add = exclWave + exclLane;
    s0 += add; s1 += add; s2 += add; s3 += add;

    // per-bucket event contribution: cnt * log(suffix); guard cnt==0
    float lsum = 0.f;
    lsum += (c4.x > 0.f) ? c4.x * __logf(s0) : 0.f;
    lsum += (c4.y > 0.f) ? c4.y * __logf(s1) : 0.f;
    lsum += (c4.z > 0.f) ? c4.z * __logf(s2) : 0.f;
    lsum += (c4.w > 0.f) ? c4.w * __logf(s3) : 0.f;
    float csum = c4.x + c4.y + c4.z + c4.w;
    float ssum = Spart;

    #pragma unroll
    for (int off = 32; off; off >>= 1) {
        lsum += __shfl_down(lsum, off, 64);
        csum += __shfl_down(csum, off, 64);
        ssum += __shfl_down(ssum, off, 64);
    }
    if (lane == 0) { wls[wid] = lsum; wcs[wid] = csum; wss[wid] = ssum; }
    __syncthreads();
    if (tid == 0) {
        float L = 0.f, C = 0.f, S = 0.f;
        #pragma unroll
        for (int w = 0; w < NW1; ++w) { L += wls[w]; C += wcs[w]; S += wss[w]; }
        out[0] = -(S - L) / C;
    }
}

extern "C" void kernel_launch(void* const* d_in, const int* in_sizes, int n_in,
                              void* d_out, int out_size, void* d_ws, size_t ws_size,
                              hipStream_t stream) {
    const float* risk    = (const float*)d_in[0];
    const int*   os      = (const int*)d_in[1];
    const int*   os_time = (const int*)d_in[2];
    float*       out     = (float*)d_out;
    float*       ws      = (float*)d_ws;
    const int N  = in_sizes[0];
    const int HB = (N + T1 * SPT - 1) / (T1 * SPT);   // 4 for N=8192

    k_hist<<<HB, T1, 0, stream>>>(risk, os, os_time, ws, N, HB);
    if (HB == 4)      k_final<4><<<1, T1, 0, stream>>>(ws, out, HB);
    else if (HB == 8) k_final<8><<<1, T1, 0, stream>>>(ws, out, HB);
    else              k_final<0><<<1, T1, 0, stream>>>(ws, out, HB);
}